// Round 1
// baseline (369.813 us; speedup 1.0000x reference)
//
#include <hip/hip_runtime.h>
#include <stdint.h>

#define NUM_CLASSES 21
#define NFG 20                  // foreground classes
#define TOPK 200
#define KPRE 256
#define CONF_TH 0.01f
#define NMS_TH 0.45f
#define VAR0 0.1f
#define VAR1 0.2f

// Kernel 1: per-(b,p) softmax over 21 classes, write fg probs transposed
// to ws as [B][NFG][P] so the per-class scan in kernel 2 is contiguous.
__global__ void softmax_probs_kernel(const float* __restrict__ conf,
                                     float* __restrict__ probs,
                                     int B, int P) {
    int gid = blockIdx.x * blockDim.x + threadIdx.x;
    if (gid >= B * P) return;
    int b = gid / P;
    int p = gid - b * P;
    const float* cp = conf + (size_t)gid * NUM_CLASSES;
    float x[NUM_CLASSES];
    float m = cp[0];
    x[0] = m;
#pragma unroll
    for (int j = 1; j < NUM_CLASSES; ++j) {
        x[j] = cp[j];
        m = fmaxf(m, x[j]);
    }
    float s = 0.f;
#pragma unroll
    for (int j = 0; j < NUM_CLASSES; ++j) {
        x[j] = expf(x[j] - m);
        s += x[j];
    }
#pragma unroll
    for (int c = 1; c < NUM_CLASSES; ++c) {
        probs[((size_t)b * NFG + (c - 1)) * P + p] = x[c] / s;
    }
}

// Kernel 2: one block per (b, fg_class). Top-256 selection (exact JAX top_k
// semantics via (score_bits<<32)|~idx keys), candidate box decode, sequential
// NMS scan, emit TOPK rows of (score,x1,y1,x2,y2).
__global__ __launch_bounds__(KPRE) void nms_topk_kernel(
    const float* __restrict__ probs,
    const float* __restrict__ loc,
    const float* __restrict__ prior,
    float* __restrict__ out,
    int B, int P) {
    __shared__ unsigned long long cur[KPRE];   // running top-256, sorted desc
    __shared__ unsigned long long chk[KPRE];   // current chunk
    __shared__ float sc[KPRE];
    __shared__ float bx0[KPRE], by0[KPRE], bx1[KPRE], by1[KPRE], barea[KPRE];
    __shared__ int keep[KPRE];
    __shared__ int scan[KPRE];
    __shared__ int s_total;

    const int t = threadIdx.x;
    const int pair = blockIdx.x;          // b*NFG + c
    const int b = pair / NFG;
    const float* sp = probs + (size_t)pair * P;

    cur[t] = 0ULL;
    __syncthreads();

    const int nchunks = (P + KPRE - 1) / KPRE;
    for (int ch = 0; ch < nchunks; ++ch) {
        int p = ch * KPRE + t;
        unsigned long long key = 0ULL;
        if (p < P) {
            unsigned int vb = __float_as_uint(sp[p]);   // softmax prob > 0
            key = ((unsigned long long)vb << 32) | (unsigned int)(~p);
        }
        chk[t] = key;
        __syncthreads();
        // bitonic sort chunk, descending
        for (int k = 2; k <= KPRE; k <<= 1) {
            for (int j = k >> 1; j > 0; j >>= 1) {
                int ixj = t ^ j;
                if (ixj > t) {
                    bool up = ((t & k) == 0);
                    unsigned long long a = chk[t], bb = chk[ixj];
                    bool sw = up ? (a < bb) : (a > bb);
                    if (sw) { chk[t] = bb; chk[ixj] = a; }
                }
                __syncthreads();
            }
        }
        // Batcher top-k merge: elementwise max against reversed chunk → bitonic
        unsigned long long m0 = cur[t];
        unsigned long long m1 = chk[KPRE - 1 - t];
        cur[t] = (m0 > m1) ? m0 : m1;
        __syncthreads();
        // bitonic cleaner, descending
        for (int j = KPRE >> 1; j > 0; j >>= 1) {
            int ixj = t ^ j;
            if (ixj > t) {
                unsigned long long a = cur[t], bb = cur[ixj];
                if (a < bb) { cur[t] = bb; cur[ixj] = a; }
            }
            __syncthreads();
        }
    }

    // extract candidate t (P > KPRE, so every slot is a real prior)
    unsigned long long key = cur[t];
    float v = __uint_as_float((unsigned int)(key >> 32));
    int idx = (int)(~(unsigned int)(key & 0xFFFFFFFFu));

    // decode box (matches reference op order)
    const float* lp = loc + ((size_t)b * P + idx) * 4;
    const float* pp = prior + (size_t)idx * 4;
    float l0 = lp[0], l1 = lp[1], l2 = lp[2], l3 = lp[3];
    float p0 = pp[0], p1 = pp[1], p2 = pp[2], p3 = pp[3];
    float cx = p0 + (l0 * VAR0) * p2;
    float cy = p1 + (l1 * VAR0) * p3;
    float w = p2 * expf(l2 * VAR1);
    float h = p3 * expf(l3 * VAR1);
    float x1 = cx - w * 0.5f;
    float y1 = cy - h * 0.5f;
    float x2 = x1 + w;
    float y2 = y1 + h;

    sc[t] = v;
    bx0[t] = x1; by0[t] = y1; bx1[t] = x2; by1[t] = y2;
    barea[t] = fmaxf(x2 - x1, 0.f) * fmaxf(y2 - y1, 0.f);
    keep[t] = (v > CONF_TH) ? 1 : 0;
    __syncthreads();

    // sequential suppression scan: kept box i suppresses later overlapping boxes
    for (int i = 0; i < KPRE; ++i) {
        if (keep[i] && t > i) {
            float lx = fmaxf(bx0[i], bx0[t]);
            float ly = fmaxf(by0[i], by0[t]);
            float rx = fminf(bx1[i], bx1[t]);
            float ry = fminf(by1[i], by1[t]);
            float iw = fmaxf(rx - lx, 0.f);
            float ih = fmaxf(ry - ly, 0.f);
            float inter = iw * ih;
            float uni = barea[i] + barea[t] - inter;
            float iou = inter / fmaxf(uni, 1e-9f);
            if (iou > NMS_TH) keep[t] = 0;
        }
        __syncthreads();
    }

    // rank = exclusive prefix sum of keep (Hillis-Steele, double-barrier)
    scan[t] = keep[t];
    __syncthreads();
    for (int off = 1; off < KPRE; off <<= 1) {
        int v2 = (t >= off) ? scan[t - off] : 0;
        __syncthreads();
        scan[t] += v2;
        __syncthreads();
    }
    if (t == KPRE - 1) s_total = scan[t];
    __syncthreads();
    int rank = scan[t] - keep[t];

    float* orow = out + (size_t)pair * TOPK * 5;
    if (keep[t] && rank < TOPK) {
        float* o = orow + rank * 5;
        o[0] = sc[t]; o[1] = bx0[t]; o[2] = by0[t]; o[3] = bx1[t]; o[4] = by1[t];
    }
    int total = s_total;
    if (t < TOPK && t >= total) {
        float* o = orow + t * 5;
        o[0] = 0.f; o[1] = 0.f; o[2] = 0.f; o[3] = 0.f; o[4] = 0.f;
    }
}

extern "C" void kernel_launch(void* const* d_in, const int* in_sizes, int n_in,
                              void* d_out, int out_size, void* d_ws, size_t ws_size,
                              hipStream_t stream) {
    const float* loc = (const float*)d_in[0];
    const float* conf = (const float*)d_in[1];
    const float* prior = (const float*)d_in[2];
    float* out = (float*)d_out;
    float* probs = (float*)d_ws;   // [B][NFG][P] floats = 22.35 MB

    int P = in_sizes[2] / 4;                // 8732
    int B = in_sizes[0] / (4 * P);          // 32

    int threads = 256;
    int blocks1 = (B * P + threads - 1) / threads;
    softmax_probs_kernel<<<blocks1, threads, 0, stream>>>(conf, probs, B, P);

    nms_topk_kernel<<<B * NFG, KPRE, 0, stream>>>(probs, loc, prior, out, B, P);
}

// Round 2
// 262.589 us; speedup vs baseline: 1.4083x; 1.4083x over previous
//
#include <hip/hip_runtime.h>
#include <stdint.h>

typedef unsigned long long ull;

#define NUM_CLASSES 21
#define NFG 20
#define TOPK 200
#define KPRE 256
#define CONF_TH 0.01f
#define NMS_TH 0.45f
#define VAR0 0.1f
#define VAR1 0.2f
#define NVMAX 35                 // ceil(8732/256)

// Kernel 1: per-(b,p) softmax over 21 classes; LDS-staged coalesced loads.
// Writes fg probs transposed to ws as [B][NFG][P].
__global__ __launch_bounds__(256) void softmax_probs_kernel(
    const float* __restrict__ conf, float* __restrict__ probs, int B, int P) {
    __shared__ float buf[256 * NUM_CLASSES];
    const int t = threadIdx.x;
    const int gid0 = blockIdx.x << 8;
    const int tot = B * P;
    int cnt = tot - gid0; if (cnt > 256) cnt = 256;
    const int n = cnt * NUM_CLASSES;
    const float* src = conf + (size_t)gid0 * NUM_CLASSES;
    for (int i = t; i < n; i += 256) buf[i] = src[i];
    __syncthreads();
    if (t < cnt) {
        int gid = gid0 + t;
        int b = gid / P;
        int p = gid - b * P;
        float x[NUM_CLASSES];
        float m = buf[t * NUM_CLASSES];
        x[0] = m;
#pragma unroll
        for (int j = 1; j < NUM_CLASSES; ++j) {
            x[j] = buf[t * NUM_CLASSES + j];
            m = fmaxf(m, x[j]);
        }
        float s = 0.f;
#pragma unroll
        for (int j = 0; j < NUM_CLASSES; ++j) {
            x[j] = expf(x[j] - m);
            s += x[j];
        }
#pragma unroll
        for (int c = 1; c < NUM_CLASSES; ++c) {
            probs[((size_t)b * NFG + (c - 1)) * P + p] = x[c] / s;  // true div: match ref ulps
        }
    }
}

// Kernel 2: one block per (b, fg_class).
// Phase A: scores -> registers. Phase B: radix binary-search the 256th value.
// Phase C: gather >=T (cap 512). Phase D: one bitonic sort (exact JAX tie order).
// Phase E: decode boxes. Phase F: wave-tiled NMS (shfl serial, no barrier loop).
__global__ __launch_bounds__(KPRE) void nms_topk_kernel(
    const float* __restrict__ probs, const float* __restrict__ loc,
    const float* __restrict__ prior, float* __restrict__ out, int B, int P) {

    __shared__ ull arr[2 * KPRE];      // gathered keys / sorted candidates
    __shared__ int wsum[2][4];
    __shared__ int s_cnt;
    __shared__ float4 sbox[KPRE];
    __shared__ float ssc[KPRE];
    __shared__ ull kept_mask[4];

    const int t = threadIdx.x;
    const int lane = t & 63;
    const int wid = t >> 6;
    const int pair = blockIdx.x;          // b*NFG + c
    const int b = pair / NFG;
    const float* sp = probs + (size_t)pair * P;

    // A: load scores into registers (coalesced: lane-contiguous p)
    const int nv = min((P + KPRE - 1) >> 8, NVMAX);
    unsigned int ubits[NVMAX];
    for (int i = 0; i < nv; ++i) {
        int p = (i << 8) + t;
        ubits[i] = (p < P) ? __float_as_uint(sp[p]) : 0u;
    }

    if (t == 0) s_cnt = 0;

    // B: binary search over positive-float bit space for largest T with
    // count(bits >= T) >= 256.  One barrier per iteration (double-buffered sums).
    unsigned int lo = 0u, hi = 0x80000000u;
    int it = 0;
    while (hi - lo > 1u) {
        unsigned int mid = lo + ((hi - lo) >> 1);
        int c = 0;
        for (int i = 0; i < nv; ++i) c += (ubits[i] >= mid) ? 1 : 0;
        for (int off = 32; off > 0; off >>= 1) c += __shfl_down(c, off);
        if (lane == 0) wsum[it & 1][wid] = c;
        __syncthreads();
        int totc = wsum[it & 1][0] + wsum[it & 1][1] + wsum[it & 1][2] + wsum[it & 1][3];
        if (totc >= KPRE) lo = mid; else hi = mid;
        ++it;
    }
    const unsigned int T = lo;

    // C: gather all candidates with bits >= T (slot order fixed by sort below)
    for (int i = 0; i < nv; ++i) {
        int p = (i << 8) + t;
        if (p < P && ubits[i] >= T) {
            int slot = atomicAdd(&s_cnt, 1);
            if (slot < 2 * KPRE)
                arr[slot] = ((ull)ubits[i] << 32) | (unsigned int)(~p);
        }
    }
    __syncthreads();
    const int nval = min(s_cnt, 2 * KPRE);   // guaranteed >= 256
    for (int e = t; e < 2 * KPRE; e += KPRE)
        if (e >= nval) arr[e] = 0ULL;
    __syncthreads();

    // D: bitonic sort 512 keys descending (value desc, index asc)
    for (int k = 2; k <= 2 * KPRE; k <<= 1) {
        for (int j = k >> 1; j > 0; j >>= 1) {
            for (int e = t; e < 2 * KPRE; e += KPRE) {
                int ixj = e ^ j;
                if (ixj > e) {
                    ull a = arr[e], bb = arr[ixj];
                    bool up = ((e & k) == 0);
                    if (up ? (a < bb) : (a > bb)) { arr[e] = bb; arr[ixj] = a; }
                }
            }
            __syncthreads();
        }
    }

    // E: decode candidate t (top-256 of the sort)
    ull key = arr[t];
    float v = __uint_as_float((unsigned int)(key >> 32));
    int idx = (int)(~(unsigned int)(key & 0xFFFFFFFFu));
    if (idx < 0 || idx >= P) { idx = 0; v = 0.f; }   // safety (nval>=256 in practice)

    const float4 lv = *(const float4*)(loc + ((size_t)b * P + idx) * 4);
    const float4 pv = *(const float4*)(prior + (size_t)idx * 4);
    float cx = pv.x + (lv.x * VAR0) * pv.z;
    float cy = pv.y + (lv.y * VAR0) * pv.w;
    float w = pv.z * expf(lv.z * VAR1);
    float h = pv.w * expf(lv.w * VAR1);
    float x1 = cx - w * 0.5f;
    float y1 = cy - h * 0.5f;
    float x2 = x1 + w;
    float y2 = y1 + h;
    float myarea = fmaxf(x2 - x1, 0.f) * fmaxf(y2 - y1, 0.f);

    ssc[t] = v;
    sbox[t] = make_float4(x1, y1, x2, y2);
    __syncthreads();

    // F1: per-thread suppression masks (lower triangle only; LDS broadcast reads)
    ull m[4] = {0ULL, 0ULL, 0ULL, 0ULL};
    for (int w2 = 0; w2 <= wid; ++w2) {
        ull mm = 0ULL;
        for (int i = 0; i < 64; ++i) {
            int g = (w2 << 6) + i;
            float4 gb = sbox[g];
            float ga = fmaxf(gb.z - gb.x, 0.f) * fmaxf(gb.w - gb.y, 0.f);
            float lx = fmaxf(gb.x, x1), ly = fmaxf(gb.y, y1);
            float rx = fminf(gb.z, x2), ry = fminf(gb.w, y2);
            float iw = fmaxf(rx - lx, 0.f), ih = fmaxf(ry - ly, 0.f);
            float inter = iw * ih;
            float uni = ga + myarea - inter;
            bool s = (inter / fmaxf(uni, 1e-9f)) > NMS_TH;
            mm |= ((ull)(s ? 1u : 0u)) << i;
        }
        m[w2] = mm;
    }
    m[wid] &= (lane == 0) ? 0ULL : (~0ULL >> (64 - lane));  // only i < my position

    // F2: tile-serial resolution; within-tile via shfl register loop
    int alive = (v > CONF_TH) ? 1 : 0;
    for (int w2 = 0; w2 < 4; ++w2) {
        if (wid == w2) {
            for (int w3 = 0; w3 < w2; ++w3)
                if (m[w3] & kept_mask[w3]) alive = 0;
            ull mw = m[w2];
            for (int i = 0; i < 64; ++i) {
                int ai = __shfl(alive, i);       // lane i is final at iteration i
                if (ai && ((mw >> i) & 1ULL)) alive = 0;
            }
            ull km = __ballot(alive != 0);
            if (lane == 0) kept_mask[w2] = km;
        }
        __syncthreads();
    }

    // G: rank via popcounts, write kept rows + zero-fill
    int rank = 0;
    for (int w2 = 0; w2 < wid; ++w2) rank += __popcll(kept_mask[w2]);
    rank += __popcll(kept_mask[wid] & ((lane == 0) ? 0ULL : (~0ULL >> (64 - lane))));
    int total = 0;
    for (int w2 = 0; w2 < 4; ++w2) total += __popcll(kept_mask[w2]);

    float* orow = out + (size_t)pair * TOPK * 5;
    if (alive && rank < TOPK) {
        float* o = orow + rank * 5;
        o[0] = v; o[1] = x1; o[2] = y1; o[3] = x2; o[4] = y2;
    }
    if (t < TOPK && t >= total) {
        float* o = orow + t * 5;
        o[0] = 0.f; o[1] = 0.f; o[2] = 0.f; o[3] = 0.f; o[4] = 0.f;
    }
}

extern "C" void kernel_launch(void* const* d_in, const int* in_sizes, int n_in,
                              void* d_out, int out_size, void* d_ws, size_t ws_size,
                              hipStream_t stream) {
    const float* loc = (const float*)d_in[0];
    const float* conf = (const float*)d_in[1];
    const float* prior = (const float*)d_in[2];
    float* out = (float*)d_out;
    float* probs = (float*)d_ws;            // [B][NFG][P] floats = 22.35 MB

    int P = in_sizes[2] / 4;                // 8732
    int B = in_sizes[0] / (4 * P);          // 32

    int blocks1 = (B * P + 255) / 256;
    softmax_probs_kernel<<<blocks1, 256, 0, stream>>>(conf, probs, B, P);
    nms_topk_kernel<<<B * NFG, KPRE, 0, stream>>>(probs, loc, prior, out, B, P);
}

// Round 3
// 153.960 us; speedup vs baseline: 2.4020x; 1.7056x over previous
//
#include <hip/hip_runtime.h>
#include <stdint.h>

typedef unsigned long long ull;

#define NUM_CLASSES 21
#define NFG 20
#define TOPK 200
#define KPRE 256
#define CONF_TH 0.01f
#define NMS_TH 0.45f
#define VAR0 0.1f
#define VAR1 0.2f
#define NVMAX 35                 // ceil(8732/256); assumes P <= NVMAX*256

// Kernel 1: per-(b,p) softmax over 21 classes; LDS-staged coalesced loads.
// Writes fg probs transposed to ws as [B][NFG][P].
__global__ __launch_bounds__(256) void softmax_probs_kernel(
    const float* __restrict__ conf, float* __restrict__ probs, int B, int P) {
    __shared__ float buf[256 * NUM_CLASSES];
    const int t = threadIdx.x;
    const int gid0 = blockIdx.x << 8;
    const int tot = B * P;
    int cnt = tot - gid0; if (cnt > 256) cnt = 256;
    const int n = cnt * NUM_CLASSES;
    const float* src = conf + (size_t)gid0 * NUM_CLASSES;
    for (int i = t; i < n; i += 256) buf[i] = src[i];
    __syncthreads();
    if (t < cnt) {
        int gid = gid0 + t;
        int b = gid / P;
        int p = gid - b * P;
        float x[NUM_CLASSES];
        float m = buf[t * NUM_CLASSES];
        x[0] = m;
#pragma unroll
        for (int j = 1; j < NUM_CLASSES; ++j) {
            x[j] = buf[t * NUM_CLASSES + j];
            m = fmaxf(m, x[j]);
        }
        float s = 0.f;
#pragma unroll
        for (int j = 0; j < NUM_CLASSES; ++j) {
            x[j] = expf(x[j] - m);
            s += x[j];
        }
#pragma unroll
        for (int c = 1; c < NUM_CLASSES; ++c) {
            probs[((size_t)b * NFG + (c - 1)) * P + p] = x[c] / s;  // true div: match ref ulps
        }
    }
}

// Kernel 2: one block per (b, fg_class).
// A: scores -> VGPRs (compile-time unrolled => NO scratch spill; VGPR_Count
//    was 24 last round = ubits spilled, 23 MB of scratch writes).
// B: 31-iter binary search over fp32 bit space for the 256th value.
// C: ballot-compaction gather (1 LDS atomic per wave).
// D: hybrid shfl/LDS bitonic sort (exact JAX tie order: value desc, idx asc).
// E: decode. F: wave-tiled NMS. G: popcount ranks + write.
__global__ __launch_bounds__(KPRE) void nms_topk_kernel(
    const float* __restrict__ probs, const float* __restrict__ loc,
    const float* __restrict__ prior, float* __restrict__ out, int B, int P) {

    __shared__ ull arr[2 * KPRE];
    __shared__ int wsum[2][4];
    __shared__ int s_cnt;
    __shared__ float4 sbox[KPRE];
    __shared__ float sarea[KPRE];
    __shared__ ull kept_mask[4];

    const int t = threadIdx.x;
    const int lane = t & 63;
    const int wid = t >> 6;
    const ull lmask_lt = (1ULL << lane) - 1ULL;
    const int pair = blockIdx.x;          // b*NFG + c
    const int b = pair / NFG;
    const float* sp = probs + (size_t)pair * P;

    // A: scores into registers; constant trip count so the array stays in VGPRs
    unsigned int ubits[NVMAX];
#pragma unroll
    for (int i = 0; i < NVMAX; ++i) {
        int p = (i << 8) + t;
        ubits[i] = (p < P) ? __float_as_uint(sp[p]) : 0u;
    }

    if (t == 0) s_cnt = 0;

    // B: largest T with count(bits >= T) >= 256 (scores are positive floats)
    unsigned int lo = 0u, hi = 0x80000000u;
    int it = 0;
    while (hi - lo > 1u) {
        unsigned int mid = lo + ((hi - lo) >> 1);
        int c = 0;
#pragma unroll
        for (int i = 0; i < NVMAX; ++i) c += (ubits[i] >= mid) ? 1 : 0;
#pragma unroll
        for (int off = 32; off > 0; off >>= 1) c += __shfl_down(c, off);
        if (lane == 0) wsum[it & 1][wid] = c;
        __syncthreads();
        int totc = wsum[it & 1][0] + wsum[it & 1][1] + wsum[it & 1][2] + wsum[it & 1][3];
        if (totc >= KPRE) lo = mid; else hi = mid;
        ++it;
    }
    const unsigned int T = lo;

    // C: ballot-compaction gather of all bits >= T (cap 512; exact-256 typical)
    int wtot = 0;
#pragma unroll
    for (int i = 0; i < NVMAX; ++i) {
        int p = (i << 8) + t;
        bool pred = (p < P) && (ubits[i] >= T);
        ull bal = __ballot(pred);
        wtot += __popcll(bal);
    }
    int wbase = 0;
    if (lane == 0) wbase = atomicAdd(&s_cnt, wtot);
    wbase = __shfl(wbase, 0);
    int run = wbase;
#pragma unroll
    for (int i = 0; i < NVMAX; ++i) {
        int p = (i << 8) + t;
        bool pred = (p < P) && (ubits[i] >= T);
        ull bal = __ballot(pred);
        if (pred) {
            int slot = run + __popcll(bal & lmask_lt);
            if (slot < 2 * KPRE)
                arr[slot] = ((ull)ubits[i] << 32) | (unsigned int)(~p);
        }
        run += __popcll(bal);
    }
    __syncthreads();
    const int nval = min(s_cnt, 2 * KPRE);   // >= 256 guaranteed
    for (int e = t; e < 2 * KPRE; e += KPRE)
        if (e >= nval) arr[e] = 0ULL;
    __syncthreads();

    // D: sort descending; key = (bits<<32)|~idx  => value desc, index asc
    ull key;
    if (nval <= KPRE) {
        // hybrid bitonic over 256: shfl_xor for j<=32, LDS only for j in {64,128}
        key = arr[t];
        __syncthreads();
        for (int kk = 2; kk <= KPRE; kk <<= 1) {
            for (int j = kk >> 1; j > 0; j >>= 1) {
                bool dirDesc = ((t & kk) == 0);
                ull other;
                if (j >= 64) {
                    arr[t] = key;
                    __syncthreads();
                    other = arr[t ^ j];
                    __syncthreads();
                } else {
                    other = __shfl_xor(key, j);
                }
                bool amLow = ((t & j) == 0);
                ull mx = (key > other) ? key : other;
                ull mn = (key > other) ? other : key;
                key = (dirDesc == amLow) ? mx : mn;
            }
        }
    } else {
        // rare tie-overflow path: full LDS bitonic over 512
        for (int kk = 2; kk <= 2 * KPRE; kk <<= 1) {
            for (int j = kk >> 1; j > 0; j >>= 1) {
                for (int e = t; e < 2 * KPRE; e += KPRE) {
                    int ixj = e ^ j;
                    if (ixj > e) {
                        ull a = arr[e], bb = arr[ixj];
                        bool up = ((e & kk) == 0);
                        if (up ? (a < bb) : (a > bb)) { arr[e] = bb; arr[ixj] = a; }
                    }
                }
                __syncthreads();
            }
        }
        key = arr[t];
    }

    // E: decode candidate t
    float v = __uint_as_float((unsigned int)(key >> 32));
    int idx = (int)(~(unsigned int)(key & 0xFFFFFFFFu));
    if (idx < 0 || idx >= P) { idx = 0; v = 0.f; }   // safety

    const float4 lv = *(const float4*)(loc + ((size_t)b * P + idx) * 4);
    const float4 pv = *(const float4*)(prior + (size_t)idx * 4);
    float cx = pv.x + (lv.x * VAR0) * pv.z;
    float cy = pv.y + (lv.y * VAR0) * pv.w;
    float w = pv.z * expf(lv.z * VAR1);
    float h = pv.w * expf(lv.w * VAR1);
    float x1 = cx - w * 0.5f;
    float y1 = cy - h * 0.5f;
    float x2 = x1 + w;
    float y2 = y1 + h;
    float myarea = fmaxf(x2 - x1, 0.f) * fmaxf(y2 - y1, 0.f);

    sbox[t] = make_float4(x1, y1, x2, y2);
    sarea[t] = myarea;
    __syncthreads();

    // F1: per-thread "who-suppresses-me" masks (lower triangle only)
    ull m[4] = {0ULL, 0ULL, 0ULL, 0ULL};
    for (int w2 = 0; w2 <= wid; ++w2) {
        ull mm = 0ULL;
        for (int i = 0; i < 64; ++i) {
            int g = (w2 << 6) + i;
            float4 gb = sbox[g];
            float ga = sarea[g];
            float lx = fmaxf(gb.x, x1), ly = fmaxf(gb.y, y1);
            float rx = fminf(gb.z, x2), ry = fminf(gb.w, y2);
            float iw = fmaxf(rx - lx, 0.f), ih = fmaxf(ry - ly, 0.f);
            float inter = iw * ih;
            float uni = ga + myarea - inter;
            bool s = (inter / fmaxf(uni, 1e-9f)) > NMS_TH;
            mm |= ((ull)(s ? 1u : 0u)) << i;
        }
        m[w2] = mm;
    }
    m[wid] &= lmask_lt;   // only suppressors strictly before me

    // F2: tile-serial resolution; within-tile via shfl register loop
    int alive = (v > CONF_TH) ? 1 : 0;
    for (int w2 = 0; w2 < 4; ++w2) {
        if (wid == w2) {
            for (int w3 = 0; w3 < w2; ++w3)
                if (m[w3] & kept_mask[w3]) alive = 0;
            ull mw = m[w2];
            for (int i = 0; i < 64; ++i) {
                int ai = __shfl(alive, i);       // lane i final at iteration i
                if (ai && ((mw >> i) & 1ULL)) alive = 0;
            }
            ull km = __ballot(alive != 0);
            if (lane == 0) kept_mask[w2] = km;
        }
        __syncthreads();
    }

    // G: rank via popcounts, write kept rows + zero-fill
    int rank = 0;
    for (int w2 = 0; w2 < wid; ++w2) rank += __popcll(kept_mask[w2]);
    rank += __popcll(kept_mask[wid] & lmask_lt);
    int total = 0;
    for (int w2 = 0; w2 < 4; ++w2) total += __popcll(kept_mask[w2]);

    float* orow = out + (size_t)pair * TOPK * 5;
    if (alive && rank < TOPK) {
        float* o = orow + rank * 5;
        o[0] = v; o[1] = x1; o[2] = y1; o[3] = x2; o[4] = y2;
    }
    if (t < TOPK && t >= total) {
        float* o = orow + t * 5;
        o[0] = 0.f; o[1] = 0.f; o[2] = 0.f; o[3] = 0.f; o[4] = 0.f;
    }
}

extern "C" void kernel_launch(void* const* d_in, const int* in_sizes, int n_in,
                              void* d_out, int out_size, void* d_ws, size_t ws_size,
                              hipStream_t stream) {
    const float* loc = (const float*)d_in[0];
    const float* conf = (const float*)d_in[1];
    const float* prior = (const float*)d_in[2];
    float* out = (float*)d_out;
    float* probs = (float*)d_ws;            // [B][NFG][P] floats = 22.35 MB

    int P = in_sizes[2] / 4;                // 8732
    int B = in_sizes[0] / (4 * P);          // 32

    int blocks1 = (B * P + 255) / 256;
    softmax_probs_kernel<<<blocks1, 256, 0, stream>>>(conf, probs, B, P);
    nms_topk_kernel<<<B * NFG, KPRE, 0, stream>>>(probs, loc, prior, out, B, P);
}

// Round 4
// 151.258 us; speedup vs baseline: 2.4449x; 1.0179x over previous
//
#include <hip/hip_runtime.h>
#include <stdint.h>

typedef unsigned long long ull;

#define NUM_CLASSES 21
#define NFG 20
#define TOPK 200
#define KPRE 256
#define CONF_TH 0.01f
#define NMS_TH 0.45f
#define VAR0 0.1f
#define VAR1 0.2f
#define NVMAX 35                 // ceil(8732/256)
#define BITS_CONF 0x3C23D70Au    // __float_as_uint(0.01f)
#define BITS_ONE1 0x3F800001u    // just above 1.0f (softmax <= 1)

// Kernel 1: grid (chunks-of-256-priors, images). float4 staging in, softmax,
// LDS transpose, float4 stores out (20 scalar stores/thread was the suspected
// ~65us bottleneck). probs layout: [B][NFG][P].
__global__ __launch_bounds__(256) void softmax_probs_kernel(
    const float* __restrict__ conf, float* __restrict__ probs, int P) {
    __shared__ __align__(16) float buf[256 * NUM_CLASSES];   // 21504 B
    __shared__ __align__(16) float obuf[NFG * 256];          // 20480 B
    const int t = threadIdx.x;
    const int b = blockIdx.y;
    const int p0 = blockIdx.x << 8;
    const int cnt = min(256, P - p0);
    const float* src = conf + ((size_t)b * P + p0) * NUM_CLASSES;

    if (cnt == 256) {
        const float4* s4 = (const float4*)src;   // 21504 B offset => 16B aligned
        float4* b4 = (float4*)buf;
#pragma unroll
        for (int k = 0; k < 6; ++k) {
            int i = (k << 8) + t;
            if (i < (256 * NUM_CLASSES) / 4) b4[i] = s4[i];
        }
    } else {
        int n = cnt * NUM_CLASSES;
        for (int i = t; i < n; i += 256) buf[i] = src[i];
    }
    __syncthreads();

    if (t < cnt) {
        const float* row = buf + t * NUM_CLASSES;   // stride 21 (odd) => conflict-free
        float x[NUM_CLASSES];
        float mx = row[0];
        x[0] = mx;
#pragma unroll
        for (int j = 1; j < NUM_CLASSES; ++j) { x[j] = row[j]; mx = fmaxf(mx, x[j]); }
        float s = 0.f;
#pragma unroll
        for (int j = 0; j < NUM_CLASSES; ++j) { x[j] = expf(x[j] - mx); s += x[j]; }
#pragma unroll
        for (int c = 1; c < NUM_CLASSES; ++c)
            obuf[(c - 1) * 256 + t] = x[c] / s;     // true div: match ref ulps
    }
    __syncthreads();

    float* dst = probs + ((size_t)b * NFG) * P + p0;
    if (cnt == 256) {
        // 20 classes x 64 float4 = 1280 stores; each wave emits one contiguous
        // 1KB class segment per iteration. Row base (c*P floats) is 16B aligned.
#pragma unroll
        for (int k = 0; k < 5; ++k) {
            int e = (k << 8) + t;
            int c = e >> 6;
            int f = e & 63;
            float4 val = ((const float4*)obuf)[(c << 6) + f];
            *(float4*)(dst + (size_t)c * P + (f << 2)) = val;
        }
    } else {
        for (int e = t; e < NFG * cnt; e += 256) {
            int c = e / cnt;
            int f = e - c * cnt;
            dst[(size_t)c * P + f] = obuf[c * 256 + f];
        }
    }
}

// Kernel 2: one block per (b, fg_class).
__global__ __launch_bounds__(KPRE) void nms_topk_kernel(
    const float* __restrict__ probs, const float* __restrict__ loc,
    const float* __restrict__ prior, float* __restrict__ out, int B, int P) {

    __shared__ ull arr[2 * KPRE];
    __shared__ int wsum[2][4];
    __shared__ int s_cnt;
    __shared__ float4 sbox[KPRE];
    __shared__ float sarea[KPRE];
    __shared__ ull smask[KPRE][4];     // suppression bitmatrix (8 KB)
    __shared__ ull kept_mask[4];

    const int t = threadIdx.x;
    const int lane = t & 63;
    const int wid = t >> 6;
    const ull lmask_lt = (1ULL << lane) - 1ULL;
    const int pair = blockIdx.x;          // b*NFG + c
    const int b = pair / NFG;
    const float* sp = probs + (size_t)pair * P;

    // A: scores into registers (constant trip count => stays in VGPRs)
    unsigned int ubits[NVMAX];
#pragma unroll
    for (int i = 0; i < NVMAX; ++i) {
        int p = (i << 8) + t;
        ubits[i] = (p < P) ? __float_as_uint(sp[p]) : 0u;
    }

    if (t == 0) s_cnt = 0;

    // B: largest T in [0.01, 1.0] with count(bits >= T) >= 256. Candidates
    // below 0.01 are invalid in the reference (zero rows) so clamping lo is
    // output-equivalent. 26 iterations.
    unsigned int lo = BITS_CONF, hi = BITS_ONE1;
    int it = 0;
    while (hi - lo > 1u) {
        unsigned int mid = lo + ((hi - lo) >> 1);
        int c = 0;
#pragma unroll
        for (int i = 0; i < NVMAX; ++i) c += (ubits[i] >= mid) ? 1 : 0;
#pragma unroll
        for (int off = 32; off > 0; off >>= 1) c += __shfl_down(c, off);
        if (lane == 0) wsum[it & 1][wid] = c;
        __syncthreads();
        int totc = wsum[it & 1][0] + wsum[it & 1][1] + wsum[it & 1][2] + wsum[it & 1][3];
        if (totc >= KPRE) lo = mid; else hi = mid;
        ++it;
    }
    const unsigned int T = lo;

    // C: ballot-compaction gather (cap 512)
    int wtot = 0;
#pragma unroll
    for (int i = 0; i < NVMAX; ++i) {
        int p = (i << 8) + t;
        bool pred = (p < P) && (ubits[i] >= T);
        wtot += __popcll(__ballot(pred));
    }
    int wbase = 0;
    if (lane == 0) wbase = atomicAdd(&s_cnt, wtot);
    wbase = __shfl(wbase, 0);
    int run = wbase;
#pragma unroll
    for (int i = 0; i < NVMAX; ++i) {
        int p = (i << 8) + t;
        bool pred = (p < P) && (ubits[i] >= T);
        ull bal = __ballot(pred);
        if (pred) {
            int slot = run + __popcll(bal & lmask_lt);
            if (slot < 2 * KPRE)
                arr[slot] = ((ull)ubits[i] << 32) | (unsigned int)(~p);
        }
        run += __popcll(bal);
    }
    __syncthreads();
    const int nval = min(s_cnt, 2 * KPRE);
    for (int e = t; e < 2 * KPRE; e += KPRE)
        if (e >= nval) arr[e] = 0ULL;
    __syncthreads();

    // D: sort descending; key = (bits<<32)|~idx => value desc, index asc (JAX)
    ull key;
    if (nval <= KPRE) {
        key = arr[t];
        __syncthreads();
        for (int kk = 2; kk <= KPRE; kk <<= 1) {
            for (int j = kk >> 1; j > 0; j >>= 1) {
                bool dirDesc = ((t & kk) == 0);
                ull other;
                if (j >= 64) {
                    arr[t] = key;
                    __syncthreads();
                    other = arr[t ^ j];
                    __syncthreads();
                } else {
                    other = __shfl_xor(key, j);
                }
                bool amLow = ((t & j) == 0);
                ull mx = (key > other) ? key : other;
                ull mn = (key > other) ? other : key;
                key = (dirDesc == amLow) ? mx : mn;
            }
        }
    } else {
        for (int kk = 2; kk <= 2 * KPRE; kk <<= 1) {
            for (int j = kk >> 1; j > 0; j >>= 1) {
                for (int e = t; e < 2 * KPRE; e += KPRE) {
                    int ixj = e ^ j;
                    if (ixj > e) {
                        ull a = arr[e], bb = arr[ixj];
                        bool up = ((e & kk) == 0);
                        if (up ? (a < bb) : (a > bb)) { arr[e] = bb; arr[ixj] = a; }
                    }
                }
                __syncthreads();
            }
        }
        key = arr[t];
    }

    // E: decode candidate t
    float v = __uint_as_float((unsigned int)(key >> 32));
    int idx = (int)(~(unsigned int)(key & 0xFFFFFFFFu));
    if (idx < 0 || idx >= P) { idx = 0; v = 0.f; }

    const float4 lv = *(const float4*)(loc + ((size_t)b * P + idx) * 4);
    const float4 pv = *(const float4*)(prior + (size_t)idx * 4);
    float cx = pv.x + (lv.x * VAR0) * pv.z;
    float cy = pv.y + (lv.y * VAR0) * pv.w;
    float w = pv.z * expf(lv.z * VAR1);
    float h = pv.w * expf(lv.w * VAR1);
    float x1 = cx - w * 0.5f;
    float y1 = cy - h * 0.5f;
    float x2 = x1 + w;
    float y2 = y1 + h;
    float myarea = fmaxf(x2 - x1, 0.f) * fmaxf(y2 - y1, 0.f);

    sbox[t] = make_float4(x1, y1, x2, y2);
    sarea[t] = myarea;
    __syncthreads();

    // F1: balanced mask build. 640 (row,tile) pairs flattened over 256 threads
    // (max 3 tiles/thread vs 4 on the old triangular split).
#pragma unroll
    for (int rep = 0; rep < 3; ++rep) {
        int pid = t + (rep << 8);
        if (pid < 640) {
            int r, w2;
            if (pid < 64)       { r = pid;                w2 = 0; }
            else if (pid < 192) { int q = pid - 64;  r = 64  + (q >> 1); w2 = q & 1; }
            else if (pid < 384) { int q = pid - 192; int q3 = q / 3; r = 128 + q3; w2 = q - 3 * q3; }
            else                { int q = pid - 384; r = 192 + (q >> 2); w2 = q & 3; }
            float4 rb = sbox[r];
            float ra = sarea[r];
            ull mm = 0ULL;
            for (int i = 0; i < 64; ++i) {
                int g = (w2 << 6) + i;
                float4 gb = sbox[g];
                float lx = fmaxf(gb.x, rb.x), ly = fmaxf(gb.y, rb.y);
                float rx = fminf(gb.z, rb.z), ry = fminf(gb.w, rb.w);
                float iw = fmaxf(rx - lx, 0.f), ih = fmaxf(ry - ly, 0.f);
                float inter = iw * ih;
                float uni = sarea[g] + ra - inter;
                bool s = (inter / fmaxf(uni, 1e-9f)) > NMS_TH;
                mm |= ((ull)(s ? 1u : 0u)) << i;
            }
            smask[r][w2] = mm;
        }
    }
    __syncthreads();

    // F2: load my row's masks, resolve tile-serially (shfl within tile)
    ull m0 = smask[t][0];
    ull m1 = (wid >= 1) ? smask[t][1] : 0ULL;
    ull m2 = (wid >= 2) ? smask[t][2] : 0ULL;
    ull m3 = (wid >= 3) ? smask[t][3] : 0ULL;
    if (wid == 0) m0 &= lmask_lt;
    else if (wid == 1) m1 &= lmask_lt;
    else if (wid == 2) m2 &= lmask_lt;
    else m3 &= lmask_lt;

    int alive = (v > CONF_TH) ? 1 : 0;
#pragma unroll
    for (int w2 = 0; w2 < 4; ++w2) {
        if (wid == w2) {
            if (w2 > 0 && (m0 & kept_mask[0])) alive = 0;
            if (w2 > 1 && (m1 & kept_mask[1])) alive = 0;
            if (w2 > 2 && (m2 & kept_mask[2])) alive = 0;
            ull mw = (w2 == 0) ? m0 : (w2 == 1) ? m1 : (w2 == 2) ? m2 : m3;
            for (int i = 0; i < 64; ++i) {
                int ai = __shfl(alive, i);       // lane i final at iteration i
                if (ai && ((mw >> i) & 1ULL)) alive = 0;
            }
            ull km = __ballot(alive != 0);
            if (lane == 0) kept_mask[w2] = km;
        }
        __syncthreads();
    }

    // G: rank via popcounts, write kept rows + zero-fill
    int rank = 0;
#pragma unroll
    for (int w2 = 0; w2 < 4; ++w2)
        if (w2 < wid) rank += __popcll(kept_mask[w2]);
    rank += __popcll(((wid == 0) ? m0 : (wid == 1) ? m1 : (wid == 2) ? m2 : m3, kept_mask[wid]) & lmask_lt);
    int total = 0;
#pragma unroll
    for (int w2 = 0; w2 < 4; ++w2) total += __popcll(kept_mask[w2]);

    float* orow = out + (size_t)pair * TOPK * 5;
    if (alive && rank < TOPK) {
        float* o = orow + rank * 5;
        o[0] = v; o[1] = x1; o[2] = y1; o[3] = x2; o[4] = y2;
    }
    if (t < TOPK && t >= total) {
        float* o = orow + t * 5;
        o[0] = 0.f; o[1] = 0.f; o[2] = 0.f; o[3] = 0.f; o[4] = 0.f;
    }
}

extern "C" void kernel_launch(void* const* d_in, const int* in_sizes, int n_in,
                              void* d_out, int out_size, void* d_ws, size_t ws_size,
                              hipStream_t stream) {
    const float* loc = (const float*)d_in[0];
    const float* conf = (const float*)d_in[1];
    const float* prior = (const float*)d_in[2];
    float* out = (float*)d_out;
    float* probs = (float*)d_ws;            // [B][NFG][P] floats = 22.35 MB

    int P = in_sizes[2] / 4;                // 8732
    int B = in_sizes[0] / (4 * P);          // 32

    dim3 g1((P + 255) / 256, B);
    softmax_probs_kernel<<<g1, 256, 0, stream>>>(conf, probs, P);
    nms_topk_kernel<<<B * NFG, KPRE, 0, stream>>>(probs, loc, prior, out, B, P);
}